// Round 7
// baseline (33.655 us; speedup 1.0000x reference)
//
#include <hip/hip_runtime.h>

namespace {
constexpr int W = 512, H = 512, D = 8, B = 4;
constexpr int HW  = H * W;
constexpr int DHW = D * HW;
constexpr long YBASE = (long)B * 3 * DHW;  // coords_max elements before y_max
typedef float f32x4 __attribute__((ext_vector_type(4)));
}

struct Row3 {               // one y-row across the 3 z-slabs
  f32x4 a, b, c;            // aligned float4 at x0 for z-1, z, z+1
  float ea, eb, ec;         // wave-edge value (x=256 for half0, x=255 for half1)
};

// R4 winner (31.7us: x=4/lane, 4-row y-march, shuffle halos, early prefetch,
// LB(256,3)) with CACHED stores instead of nontemporal.
// Rationale: R3 disproved the "keep L3 for the input" premise behind NT
// (input traffic is not binding), while NT forces the dominant stream --
// 134 MB of writes -- straight to HBM on the critical path (4.2 TB/s of the
// kernel's BW budget). Cached stores land in L2/L3 (output+input = 168 MB
// < 256 MB Infinity Cache); full-line 1KB/wave writes need no RFO; the
// dirty-line drain to HBM can lag/overlap the kernel instead of gating it.
__global__ __launch_bounds__(256, 3) void cqi3d(const float* __restrict__ x,
                                                float* __restrict__ out) {
  int t = blockIdx.x * 256 + threadIdx.x;
  int lane = t & 63;
  int wid = t >> 6;              // 8192 waves
  int half = wid & 1;            // x half: 0..1
  int y0 = ((wid >> 1) & 127) << 2;
  int z  = (wid >> 8) & 7;
  int b  = wid >> 11;
  int x0 = half * 256 + lane * 4;

  int zm1 = z > 0 ? z - 1 : 0, zp1 = z < D - 1 ? z + 1 : D - 1;
  const float* sb0 = x + (size_t)b * DHW + (size_t)zm1 * HW + x0;  // z-1
  const float* sb1 = x + (size_t)b * DHW + (size_t)z   * HW + x0;  // z
  const float* sb2 = x + (size_t)b * DHW + (size_t)zp1 * HW + x0;  // z+1
  // uniform-address edge element, expressed relative to the per-lane pointer:
  // half0 -> x=256 (right edge), half1 -> x=255 (left edge)
  int eo = (half ? 255 : 256) - x0;
  int lm = lane - 1, lp = lane + 1;
  bool l0 = (lane == 0), l63 = (lane == 63);

  float w[3][3][6];  // [yslot][iz][xc], xc covers x0-1 .. x0+4

  auto fetch = [&](int yq) -> Row3 {
    int yc = yq < 0 ? 0 : (yq > H - 1 ? H - 1 : yq);
    const float* p0 = sb0 + (size_t)yc * W;
    const float* p1 = sb1 + (size_t)yc * W;
    const float* p2 = sb2 + (size_t)yc * W;
    Row3 r;
    r.a = *reinterpret_cast<const f32x4*>(p0); r.ea = p0[eo];
    r.b = *reinterpret_cast<const f32x4*>(p1); r.eb = p1[eo];
    r.c = *reinterpret_cast<const f32x4*>(p2); r.ec = p2[eo];
    return r;
  };
  auto commit = [&](int slot, const Row3& r) {
    // halos from neighbor lanes; wave-edge / global-edge handled by selects.
    float lnA = __shfl(r.a.w, lm), rnA = __shfl(r.a.x, lp);
    float lnB = __shfl(r.b.w, lm), rnB = __shfl(r.b.x, lp);
    float lnC = __shfl(r.c.w, lm), rnC = __shfl(r.c.x, lp);
    w[slot][0][0] = l0  ? (half ? r.ea : r.a.x) : lnA;
    w[slot][0][1] = r.a.x; w[slot][0][2] = r.a.y;
    w[slot][0][3] = r.a.z; w[slot][0][4] = r.a.w;
    w[slot][0][5] = l63 ? (half ? r.a.w : r.ea) : rnA;
    w[slot][1][0] = l0  ? (half ? r.eb : r.b.x) : lnB;
    w[slot][1][1] = r.b.x; w[slot][1][2] = r.b.y;
    w[slot][1][3] = r.b.z; w[slot][1][4] = r.b.w;
    w[slot][1][5] = l63 ? (half ? r.b.w : r.eb) : rnB;
    w[slot][2][0] = l0  ? (half ? r.ec : r.c.x) : lnC;
    w[slot][2][1] = r.c.x; w[slot][2][2] = r.c.y;
    w[slot][2][3] = r.c.z; w[slot][2][4] = r.c.w;
    w[slot][2][5] = l63 ? (half ? r.c.w : r.ec) : rnC;
  };

  { Row3 r = fetch(y0 - 1); commit(0, r); }
  { Row3 r = fetch(y0);     commit(1, r); }
  { Row3 r = fetch(y0 + 1); commit(2, r); }

  float zf = (float)z;
#pragma unroll
  for (int g = 0; g < 4; ++g) {
    int jm = g % 3, jc = (g + 1) % 3, jp = (g + 2) % 3;
    int y = y0 + g;

    Row3 pf;                       // prefetch y+2 BEFORE compute (hides latency)
    if (g < 3) pf = fetch(y + 2);

    const float (&wm)[3][6] = w[jm];  // y-1
    const float (&wc)[3][6] = w[jc];  // y
    const float (&wp)[3][6] = w[jp];  // y+1

    // shared column maxes over the 9 (y,z) rows
    float cm[6];
#pragma unroll
    for (int q = 0; q < 6; ++q) {
      float m0 = fmaxf(fmaxf(wm[0][q], wm[1][q]), wm[2][q]);
      float m1 = fmaxf(fmaxf(wc[0][q], wc[1][q]), wc[2][q]);
      float m2 = fmaxf(fmaxf(wp[0][q], wp[1][q]), wp[2][q]);
      cm[q] = fmaxf(fmaxf(m0, m1), m2);
    }

    float ods[4], odx[4], ody[4], oym[4];
#pragma unroll
    for (int k = 0; k < 4; ++k) {
      float c  = wc[1][k + 1];
      float bx = 0.5f * (wc[1][k + 2] - wc[1][k]);
      float by = 0.5f * (wp[1][k + 1] - wm[1][k + 1]);
      float bs = 0.5f * (wc[2][k + 1] - wc[0][k + 1]);
      float a  = wc[1][k + 2] - 2.0f * c + wc[1][k];        // dxx
      float b_ = wp[1][k + 1] - 2.0f * c + wm[1][k + 1];    // dyy
      float c_ = wc[2][k + 1] - 2.0f * c + wc[0][k + 1];    // dss
      float dxy = wm[1][k] - wm[1][k + 2] - wp[1][k] + wp[1][k + 2];
      float dys = wm[0][k + 1] - wp[0][k + 1] - wm[2][k + 1] + wp[2][k + 1];
      float dxs = wc[0][k] - wc[0][k + 2] - wc[2][k] + wc[2][k + 2];
      float d_ = 0.25f * dxy, f_ = 0.25f * dys, e_ = 0.25f * dxs;

      // adjugate solve of symmetric [[a,d,e],[d,b,f],[e,f,c]]
      float cof0 = b_ * c_ - f_ * f_;
      float cof1 = e_ * f_ - d_ * c_;
      float cof2 = d_ * f_ - e_ * b_;
      float det = a * cof0 - d_ * (d_ * c_ - f_ * e_) + e_ * cof2;
      bool ok = fabsf(det) > 1e-7f;
      float sd = ok ? det : 1.0f;
      float inv = __builtin_amdgcn_rcpf(sd);  // approx rcp; well within threshold
      float sx = (cof0 * bx + cof1 * by + cof2 * bs) * inv;
      float sy = (cof1 * bx + (a * c_ - e_ * e_) * by + (e_ * d_ - a * f_) * bs) * inv;
      float ss = (cof2 * bx + (e_ * d_ - a * f_) * by + (a * b_ - d_ * d_) * bs) * inv;

      float mx = fmaxf(fmaxf(cm[k], cm[k + 1]), cm[k + 2]);
      bool newm = (c == mx) && ok;
      float dxv = newm ? -sx : 0.0f;
      float dyv = newm ? -sy : 0.0f;
      float dsv = newm ? -ss : 0.0f;
      bool over = fmaxf(fmaxf(fabsf(dxv), fabsf(dyv)), fabsf(dsv)) > 0.7f;
      if (over) { dxv = 0.0f; dyv = 0.0f; dsv = 0.0f; }
      float dy_val = 0.5f * (bx * dxv + by * dyv + bs * dsv);
      ods[k] = dsv;
      odx[k] = dxv;
      ody[k] = dyv;
      oym[k] = c + dy_val + (newm ? 10.0f : 0.0f);
    }

    size_t s  = (size_t)z * HW + (size_t)y * W + x0;
    size_t cb = (size_t)b * 3 * DHW + s;
    float yf = (float)y, xf = (float)x0;
    // CACHED stores: output (134 MB) + input fit in the 256 MB Infinity
    // Cache; the dirty-line drain to HBM lags the kernel instead of gating
    // every store at HBM mixed-stream bandwidth (the NT behavior).
    f32x4 v0 = { ods[0] + zf, ods[1] + zf, ods[2] + zf, ods[3] + zf };
    f32x4 v1 = { odx[0] + xf, odx[1] + xf + 1.0f, odx[2] + xf + 2.0f, odx[3] + xf + 3.0f };
    f32x4 v2 = { ody[0] + yf, ody[1] + yf, ody[2] + yf, ody[3] + yf };
    f32x4 v3 = { oym[0], oym[1], oym[2], oym[3] };
    *reinterpret_cast<f32x4*>(out + cb)           = v0;
    *reinterpret_cast<f32x4*>(out + cb + DHW)     = v1;
    *reinterpret_cast<f32x4*>(out + cb + 2 * DHW) = v2;
    *reinterpret_cast<f32x4*>(out + YBASE + (size_t)b * DHW + s) = v3;

    if (g < 3) commit(jm, pf);  // retire y-1 slot, bring in y+2
  }
}

extern "C" void kernel_launch(void* const* d_in, const int* in_sizes, int n_in,
                              void* d_out, int out_size, void* d_ws, size_t ws_size,
                              hipStream_t stream) {
  const float* x = (const float*)d_in[0];
  float* out = (float*)d_out;
  // 8192 waves: (b,z,ygroup,half) -> 524288 threads
  dim3 grid(2048), block(256);
  hipLaunchKernelGGL(cqi3d, grid, block, 0, stream, x, out);
}

// Round 8
// 32.090 us; speedup vs baseline: 1.0488x; 1.0488x over previous
//
#include <hip/hip_runtime.h>

namespace {
constexpr int W = 512, H = 512, D = 8, B = 4;
constexpr int HW  = H * W;
constexpr int DHW = D * HW;
constexpr long YBASE = (long)B * 3 * DHW;  // coords_max elements before y_max
typedef float f32x4 __attribute__((ext_vector_type(4)));
}

struct Row3 {               // one y-row across the 3 z-slabs
  f32x4 a, b, c;            // aligned float4 at x0 for z-1, z, z+1
  float ea, eb, ec;         // wave-edge value (x=256 for half0, x=255 for half1)
};

// FINAL (R4 winner, 31.7us): x=4/lane, 4-row y-march, shuffle halos, early
// prefetch, LB(256,3), nontemporal stores.
// Session ledger: the binding resource is L1/TA line-touch work + the
// 3-read/4-write HBM stream mix. Probed and REGRESSED: occupancy via
// smaller tile (R1), via reg-budget/LB4 (R2,R5); fabric read traffic -2.3x
// via z-march (R3); vector-VMEM instr count -50% via scalar edge loads (R6);
// cached stores (R7 — NT wins: Infinity Cache is memory-side, cached stores
// just thrash the 4MB per-XCD L2s with the 134MB write stream).
// Probed and WON: halo loads -> cross-lane shuffles (R4: 36 strided gathers
// -> ds_bpermute on the idle LDS pipe, line-touches -2.8x).
// 168 MB mandatory traffic at 31.7us = 5.3 TB/s effective vs ~7.0 TB/s
// pure-write ceiling: at the mixed-stream roofline.
__global__ __launch_bounds__(256, 3) void cqi3d(const float* __restrict__ x,
                                                float* __restrict__ out) {
  int t = blockIdx.x * 256 + threadIdx.x;
  int lane = t & 63;
  int wid = t >> 6;              // 8192 waves
  int half = wid & 1;            // x half: 0..1
  int y0 = ((wid >> 1) & 127) << 2;
  int z  = (wid >> 8) & 7;
  int b  = wid >> 11;
  int x0 = half * 256 + lane * 4;

  int zm1 = z > 0 ? z - 1 : 0, zp1 = z < D - 1 ? z + 1 : D - 1;
  const float* sb0 = x + (size_t)b * DHW + (size_t)zm1 * HW + x0;  // z-1
  const float* sb1 = x + (size_t)b * DHW + (size_t)z   * HW + x0;  // z
  const float* sb2 = x + (size_t)b * DHW + (size_t)zp1 * HW + x0;  // z+1
  // uniform-address edge element, expressed relative to the per-lane pointer:
  // half0 -> x=256 (right edge), half1 -> x=255 (left edge)
  int eo = (half ? 255 : 256) - x0;
  int lm = lane - 1, lp = lane + 1;
  bool l0 = (lane == 0), l63 = (lane == 63);

  float w[3][3][6];  // [yslot][iz][xc], xc covers x0-1 .. x0+4

  auto fetch = [&](int yq) -> Row3 {
    int yc = yq < 0 ? 0 : (yq > H - 1 ? H - 1 : yq);
    const float* p0 = sb0 + (size_t)yc * W;
    const float* p1 = sb1 + (size_t)yc * W;
    const float* p2 = sb2 + (size_t)yc * W;
    Row3 r;
    r.a = *reinterpret_cast<const f32x4*>(p0); r.ea = p0[eo];
    r.b = *reinterpret_cast<const f32x4*>(p1); r.eb = p1[eo];
    r.c = *reinterpret_cast<const f32x4*>(p2); r.ec = p2[eo];
    return r;
  };
  auto commit = [&](int slot, const Row3& r) {
    // halos from neighbor lanes; wave-edge / global-edge handled by selects.
    float lnA = __shfl(r.a.w, lm), rnA = __shfl(r.a.x, lp);
    float lnB = __shfl(r.b.w, lm), rnB = __shfl(r.b.x, lp);
    float lnC = __shfl(r.c.w, lm), rnC = __shfl(r.c.x, lp);
    w[slot][0][0] = l0  ? (half ? r.ea : r.a.x) : lnA;
    w[slot][0][1] = r.a.x; w[slot][0][2] = r.a.y;
    w[slot][0][3] = r.a.z; w[slot][0][4] = r.a.w;
    w[slot][0][5] = l63 ? (half ? r.a.w : r.ea) : rnA;
    w[slot][1][0] = l0  ? (half ? r.eb : r.b.x) : lnB;
    w[slot][1][1] = r.b.x; w[slot][1][2] = r.b.y;
    w[slot][1][3] = r.b.z; w[slot][1][4] = r.b.w;
    w[slot][1][5] = l63 ? (half ? r.b.w : r.eb) : rnB;
    w[slot][2][0] = l0  ? (half ? r.ec : r.c.x) : lnC;
    w[slot][2][1] = r.c.x; w[slot][2][2] = r.c.y;
    w[slot][2][3] = r.c.z; w[slot][2][4] = r.c.w;
    w[slot][2][5] = l63 ? (half ? r.c.w : r.ec) : rnC;
  };

  { Row3 r = fetch(y0 - 1); commit(0, r); }
  { Row3 r = fetch(y0);     commit(1, r); }
  { Row3 r = fetch(y0 + 1); commit(2, r); }

  float zf = (float)z;
#pragma unroll
  for (int g = 0; g < 4; ++g) {
    int jm = g % 3, jc = (g + 1) % 3, jp = (g + 2) % 3;
    int y = y0 + g;

    Row3 pf;                       // prefetch y+2 BEFORE compute (hides latency)
    if (g < 3) pf = fetch(y + 2);

    const float (&wm)[3][6] = w[jm];  // y-1
    const float (&wc)[3][6] = w[jc];  // y
    const float (&wp)[3][6] = w[jp];  // y+1

    // shared column maxes over the 9 (y,z) rows
    float cm[6];
#pragma unroll
    for (int q = 0; q < 6; ++q) {
      float m0 = fmaxf(fmaxf(wm[0][q], wm[1][q]), wm[2][q]);
      float m1 = fmaxf(fmaxf(wc[0][q], wc[1][q]), wc[2][q]);
      float m2 = fmaxf(fmaxf(wp[0][q], wp[1][q]), wp[2][q]);
      cm[q] = fmaxf(fmaxf(m0, m1), m2);
    }

    float ods[4], odx[4], ody[4], oym[4];
#pragma unroll
    for (int k = 0; k < 4; ++k) {
      float c  = wc[1][k + 1];
      float bx = 0.5f * (wc[1][k + 2] - wc[1][k]);
      float by = 0.5f * (wp[1][k + 1] - wm[1][k + 1]);
      float bs = 0.5f * (wc[2][k + 1] - wc[0][k + 1]);
      float a  = wc[1][k + 2] - 2.0f * c + wc[1][k];        // dxx
      float b_ = wp[1][k + 1] - 2.0f * c + wm[1][k + 1];    // dyy
      float c_ = wc[2][k + 1] - 2.0f * c + wc[0][k + 1];    // dss
      float dxy = wm[1][k] - wm[1][k + 2] - wp[1][k] + wp[1][k + 2];
      float dys = wm[0][k + 1] - wp[0][k + 1] - wm[2][k + 1] + wp[2][k + 1];
      float dxs = wc[0][k] - wc[0][k + 2] - wc[2][k] + wc[2][k + 2];
      float d_ = 0.25f * dxy, f_ = 0.25f * dys, e_ = 0.25f * dxs;

      // adjugate solve of symmetric [[a,d,e],[d,b,f],[e,f,c]]
      float cof0 = b_ * c_ - f_ * f_;
      float cof1 = e_ * f_ - d_ * c_;
      float cof2 = d_ * f_ - e_ * b_;
      float det = a * cof0 - d_ * (d_ * c_ - f_ * e_) + e_ * cof2;
      bool ok = fabsf(det) > 1e-7f;
      float sd = ok ? det : 1.0f;
      float inv = __builtin_amdgcn_rcpf(sd);  // approx rcp; well within threshold
      float sx = (cof0 * bx + cof1 * by + cof2 * bs) * inv;
      float sy = (cof1 * bx + (a * c_ - e_ * e_) * by + (e_ * d_ - a * f_) * bs) * inv;
      float ss = (cof2 * bx + (e_ * d_ - a * f_) * by + (a * b_ - d_ * d_) * bs) * inv;

      float mx = fmaxf(fmaxf(cm[k], cm[k + 1]), cm[k + 2]);
      bool newm = (c == mx) && ok;
      float dxv = newm ? -sx : 0.0f;
      float dyv = newm ? -sy : 0.0f;
      float dsv = newm ? -ss : 0.0f;
      bool over = fmaxf(fmaxf(fabsf(dxv), fabsf(dyv)), fabsf(dsv)) > 0.7f;
      if (over) { dxv = 0.0f; dyv = 0.0f; dsv = 0.0f; }
      float dy_val = 0.5f * (bx * dxv + by * dyv + bs * dsv);
      ods[k] = dsv;
      odx[k] = dxv;
      ody[k] = dyv;
      oym[k] = c + dy_val + (newm ? 10.0f : 0.0f);
    }

    size_t s  = (size_t)z * HW + (size_t)y * W + x0;
    size_t cb = (size_t)b * 3 * DHW + s;
    float yf = (float)y, xf = (float)x0;
    // nontemporal: writes go straight to HBM (Infinity Cache is memory-side
    // anyway); avoids thrashing the 4MB per-XCD L2s with the write stream
    // (R7 measured cached stores at -6%).
    f32x4 v0 = { ods[0] + zf, ods[1] + zf, ods[2] + zf, ods[3] + zf };
    f32x4 v1 = { odx[0] + xf, odx[1] + xf + 1.0f, odx[2] + xf + 2.0f, odx[3] + xf + 3.0f };
    f32x4 v2 = { ody[0] + yf, ody[1] + yf, ody[2] + yf, ody[3] + yf };
    f32x4 v3 = { oym[0], oym[1], oym[2], oym[3] };
    __builtin_nontemporal_store(v0, reinterpret_cast<f32x4*>(out + cb));
    __builtin_nontemporal_store(v1, reinterpret_cast<f32x4*>(out + cb + DHW));
    __builtin_nontemporal_store(v2, reinterpret_cast<f32x4*>(out + cb + 2 * DHW));
    __builtin_nontemporal_store(v3, reinterpret_cast<f32x4*>(out + YBASE + (size_t)b * DHW + s));

    if (g < 3) commit(jm, pf);  // retire y-1 slot, bring in y+2
  }
}

extern "C" void kernel_launch(void* const* d_in, const int* in_sizes, int n_in,
                              void* d_out, int out_size, void* d_ws, size_t ws_size,
                              hipStream_t stream) {
  const float* x = (const float*)d_in[0];
  float* out = (float*)d_out;
  // 8192 waves: (b,z,ygroup,half) -> 524288 threads
  dim3 grid(2048), block(256);
  hipLaunchKernelGGL(cqi3d, grid, block, 0, stream, x, out);
}